// Round 4
// baseline (1713.737 us; speedup 1.0000x reference)
//
#include <hip/hip_runtime.h>
#include <hip/hip_fp16.h>

// LaplacianKnn:  y'[i] = a*y[i] + b * sum_j m_e * y[nbr_e],  out = dot(x, y_nu)
// R6: gathers L2-hit, request-limited ~237us/pass (0.22 lane-req/cy/CU).
// R7: sc0 L1-bypass null. R2-ctrl: grid-stride @1/8 grid also 237 -> not ILP.
// R8: scatter via device atomics = 6.5x worse (memory-side, past XCD L2s).
// R9: coop mega-kernel: phases 2.1x slower (~500us each) despite same
//     occupancy -> cooperative machinery suspect; no per-phase counters.
// R10: same fusion WITHOUT cooperative API: ordinary launch, hand-rolled
//     sense-reversing grid barrier (device-scope atomics, generation counter,
//     replay-safe: gen only needs monotonicity). Explicit __threadfence pair
//     per block = minimum cross-XCD coherence (release-wbl2 / acquire-inv).
//     Co-residency of 2048 blocks @8/CU proven by R9's successful coop run.
//     Fork: ~760-810 total (coop API was culprit) vs ~1500 (structural).

typedef float __attribute__((ext_vector_type(4))) floatx4;
typedef unsigned int uint32;

static constexpr int BLOCK = 256;

// ---- global barrier state: device globals, replay-safe (gen monotonic) ----
__device__ int g_cnt = 0;
__device__ int g_gen = 0;

__device__ __forceinline__ void grid_barrier(int nb) {
  __syncthreads();
  if (threadIdx.x == 0) {
    __threadfence();  // release: writeback this XCD's L2 so others see our stores
    int g = __hip_atomic_load(&g_gen, __ATOMIC_RELAXED, __HIP_MEMORY_SCOPE_AGENT);
    if (__hip_atomic_fetch_add(&g_cnt, 1, __ATOMIC_ACQ_REL,
                               __HIP_MEMORY_SCOPE_AGENT) == nb - 1) {
      __hip_atomic_store(&g_cnt, 0, __ATOMIC_RELAXED, __HIP_MEMORY_SCOPE_AGENT);
      __hip_atomic_fetch_add(&g_gen, 1, __ATOMIC_RELEASE, __HIP_MEMORY_SCOPE_AGENT);
    } else {
      while (__hip_atomic_load(&g_gen, __ATOMIC_RELAXED,
                               __HIP_MEMORY_SCOPE_AGENT) == g)
        __builtin_amdgcn_s_sleep(32);
    }
    __threadfence();  // acquire: invalidate so we see other XCDs' stores
  }
  __syncthreads();
}

// ============================ mega kernel v2 ============================
__global__ __launch_bounds__(256) void mega2_kernel(
    const float* __restrict__ x, const int* __restrict__ nbr,
    const float* __restrict__ dist,
    const float* __restrict__ eps_p, const float* __restrict__ k_p,
    const int* __restrict__ nu_p,
    uint32* __restrict__ pk, __half2* __restrict__ z4,
    float* __restrict__ y1, float* __restrict__ y2,
    float* __restrict__ out, int n_edges, int nblocks) {
  __shared__ float bsum;
  const int tid = blockIdx.x * BLOCK + threadIdx.x;
  const int nth = nblocks * BLOCK;
  const float inv_eps = 1.0f / eps_p[0];
  const float kk = k_p[0];
  const float a = 4.0f * inv_eps + 2.0f * (float)nu_p[0] / (kk * kk) + 10.0f;
  const float b = -4.0f * inv_eps;
  const float bq = b * (1.0f / 4096.0f);

  // ---- P0: z4[i] = half2(1/rowsum exp(-d/eps), x[i]); 4 edges/thread ----
  const int nq = n_edges >> 2;
  for (int t = tid; t < nq; t += nth) {
    floatx4 d = __builtin_nontemporal_load((const floatx4*)(dist + (t << 2)));
    float s = __expf(-d.x * inv_eps) + __expf(-d.y * inv_eps) +
              __expf(-d.z * inv_eps) + __expf(-d.w * inv_eps);
    #pragma unroll
    for (int off = 4; off > 0; off >>= 1) s += __shfl_down(s, off, 8);
    if ((t & 7) == 0) {
      int node = t >> 3;
      z4[node] = __halves2half2(__float2half(1.0f / s), __float2half(x[node]));
    }
  }
  grid_barrier(nblocks);

  // ---- P1: fused pack + y1 = L x (one 4B gather/edge from 4MB z4) ----
  for (int e = tid; e < n_edges; e += nth) {
    int j = __builtin_nontemporal_load(nbr + e);
    float d = __builtin_nontemporal_load(dist + e);
    __half2 z = z4[j];                               // gather, L2-resident
    float t = __expf(-d * inv_eps) * __low2float(z); // t_e = exp * Dinv[j]
    float g = t * __high2float(z);                   // t_e * x[j]
    float s = t;
    #pragma unroll
    for (int off = 1; off < 32; off <<= 1) s += __shfl_xor(s, off, 32);
    float inv_s = 1.0f / s;
    uint32 mq = (uint32)__float2uint_rn(t * 4096.0f * inv_s);
    if (mq > 4095u) mq = 4095u;
    __builtin_nontemporal_store(((uint32)j << 12) | mq, pk + e);
    #pragma unroll
    for (int off = 16; off > 0; off >>= 1) g += __shfl_down(g, off, 32);
    if ((threadIdx.x & 31) == 0) {
      int node = e >> 5;
      y1[node] = a * x[node] + b * g * inv_s;
    }
  }
  grid_barrier(nblocks);

  // ---- P2: y2 = L y1 ----
  for (int e = tid; e < n_edges; e += nth) {
    uint32 p = __builtin_nontemporal_load(pk + e);
    float g = (float)(p & 0xFFFu) * y1[p >> 12];     // gather, L2-resident
    #pragma unroll
    for (int off = 16; off > 0; off >>= 1) g += __shfl_down(g, off, 32);
    if ((threadIdx.x & 31) == 0) {
      int node = e >> 5;
      y2[node] = a * y1[node] + bq * g;
    }
  }
  grid_barrier(nblocks);

  // ---- P3: out = sum x[i] * (L y2)[i] ----
  if (threadIdx.x == 0) bsum = 0.0f;
  __syncthreads();
  float acc = 0.0f;
  for (int e = tid; e < n_edges; e += nth) {
    uint32 p = __builtin_nontemporal_load(pk + e);
    float g = (float)(p & 0xFFFu) * y2[p >> 12];     // gather, L2-resident
    #pragma unroll
    for (int off = 16; off > 0; off >>= 1) g += __shfl_down(g, off, 32);
    if ((threadIdx.x & 31) == 0) {
      int node = e >> 5;
      acc += x[node] * (a * y2[node] + bq * g);
    }
  }
  if ((threadIdx.x & 31) == 0) atomicAdd(&bsum, acc);
  __syncthreads();
  if (threadIdx.x == 0) atomicAdd(out, bsum);
}

// ===================== fallback: proven 4-kernel path =====================
__global__ __launch_bounds__(256) void dinv_kernel(
    const float* __restrict__ dist, const float* __restrict__ x,
    const float* __restrict__ eps_p,
    __half2* __restrict__ z4, int n_edges) {
  int t = blockIdx.x * BLOCK + threadIdx.x;
  int e4 = t << 2;
  if (e4 >= n_edges) return;
  float inv_eps = 1.0f / eps_p[0];
  floatx4 d = __builtin_nontemporal_load((const floatx4*)(dist + e4));
  float s = __expf(-d.x * inv_eps) + __expf(-d.y * inv_eps) +
            __expf(-d.z * inv_eps) + __expf(-d.w * inv_eps);
  #pragma unroll
  for (int off = 4; off > 0; off >>= 1) s += __shfl_down(s, off, 8);
  if ((t & 7) == 0) {
    int node = t >> 3;
    z4[node] = __halves2half2(__float2half(1.0f / s), __float2half(x[node]));
  }
}

__global__ __launch_bounds__(256) void fsweep_kernel(
    const float* __restrict__ dist, const int* __restrict__ nbr,
    const __half2* __restrict__ z4,
    const float* __restrict__ x, const float* __restrict__ eps_p,
    const float* __restrict__ k_p, const int* __restrict__ nu_p,
    uint32* __restrict__ pk, float* __restrict__ yout, int n_edges) {
  int e = blockIdx.x * BLOCK + threadIdx.x;
  if (e >= n_edges) return;
  float inv_eps = 1.0f / eps_p[0];
  int j = __builtin_nontemporal_load(nbr + e);
  float d = __builtin_nontemporal_load(dist + e);
  __half2 z = z4[j];
  float t = __expf(-d * inv_eps) * __low2float(z);
  float g = t * __high2float(z);
  float s = t;
  #pragma unroll
  for (int off = 1; off < 32; off <<= 1) s += __shfl_xor(s, off, 32);
  float inv_s = 1.0f / s;
  uint32 mq = (uint32)__float2uint_rn(t * 4096.0f * inv_s);
  if (mq > 4095u) mq = 4095u;
  __builtin_nontemporal_store(((uint32)j << 12) | mq, pk + e);
  #pragma unroll
  for (int off = 16; off > 0; off >>= 1) g += __shfl_down(g, off, 32);
  if ((threadIdx.x & 31) == 0) {
    int node = e >> 5;
    float kk = k_p[0];
    float a = 4.0f * inv_eps + 2.0f * (float)nu_p[0] / (kk * kk) + 10.0f;
    float b = -4.0f * inv_eps;
    yout[node] = a * x[node] + b * g * inv_s;
  }
}

template <bool LAST>
__global__ __launch_bounds__(256) void sweep_kernel(
    const uint32* __restrict__ pk,
    const float* __restrict__ yin, float* __restrict__ yout,
    const float* __restrict__ x,
    const float* __restrict__ eps_p, const float* __restrict__ k_p,
    const int* __restrict__ nu_p,
    float* __restrict__ out, int n_edges) {
  __shared__ float bsum;
  if (LAST) { if (threadIdx.x == 0) bsum = 0.0f; __syncthreads(); }
  float inv_eps = 1.0f / eps_p[0];
  float kk = k_p[0];
  float a  = 4.0f * inv_eps + 2.0f * (float)nu_p[0] / (kk * kk) + 10.0f;
  float bq = -4.0f * inv_eps * (1.0f / 4096.0f);
  int stride = gridDim.x * BLOCK;
  for (int e = blockIdx.x * BLOCK + threadIdx.x; e < n_edges; e += stride) {
    uint32 p = __builtin_nontemporal_load(pk + e);
    float g = (float)(p & 0xFFFu) * yin[p >> 12];
    #pragma unroll
    for (int off = 16; off > 0; off >>= 1) g += __shfl_down(g, off, 32);
    if ((threadIdx.x & 31) == 0) {
      int node = e >> 5;
      float ynew = a * yin[node] + bq * g;
      if (LAST) atomicAdd(&bsum, x[node] * ynew);
      else yout[node] = ynew;
    }
  }
  if (LAST) { __syncthreads(); if (threadIdx.x == 0) atomicAdd(out, bsum); }
}

extern "C" void kernel_launch(void* const* d_in, const int* in_sizes, int n_in,
                              void* d_out, int out_size, void* d_ws, size_t ws_size,
                              hipStream_t stream) {
  const float* x     = (const float*)d_in[0];
  const int*   nbr   = (const int*)d_in[1];
  const float* dist  = (const float*)d_in[2];
  const float* eps_p = (const float*)d_in[3];
  const float* k_p   = (const float*)d_in[4];
  const int*   nu_p  = (const int*)d_in[5];
  float* out = (float*)d_out;

  int n  = in_sizes[0];   // 1,000,000 nodes  (< 2^20 -> 20-bit index fits)
  int ne = in_sizes[1];   // 32,000,000 edges

  uint32* pk   = (uint32*)d_ws;         // [ne]  packed edges
  __half2* z4  = (__half2*)(pk + ne);   // [n]   (Dinv, x) in f16
  float* y1    = (float*)(z4 + n);      // [n]
  float* y2    = y1 + n;                // [n]

  (void)hipMemsetAsync(d_out, 0, sizeof(float), stream);

  // co-resident grid (R9 proved 8 blocks/CU x 256 CU resident on this chip)
  static int grid_co = 0;
  if (grid_co == 0) {
    int nb = 0;
    if (hipOccupancyMaxActiveBlocksPerMultiprocessor(&nb, mega2_kernel, BLOCK, 0)
            != hipSuccess || nb < 1)
      nb = 0;
    if (nb > 8) nb = 8;
    grid_co = (nb > 0) ? nb * 256 : -1;
  }

  if (grid_co > 0) {
    mega2_kernel<<<grid_co, BLOCK, 0, stream>>>(
        x, nbr, dist, eps_p, k_p, nu_p, pk, z4, y1, y2, out, ne, grid_co);
  } else {
    // proven 4-kernel fallback (R1 structure, 891us)
    int gridE = (ne + BLOCK - 1) / BLOCK;
    int grid4 = (ne + BLOCK * 4 - 1) / (BLOCK * 4);
    dinv_kernel<<<grid4, BLOCK, 0, stream>>>(dist, x, eps_p, z4, ne);
    fsweep_kernel<<<gridE, BLOCK, 0, stream>>>(dist, nbr, z4, x, eps_p, k_p, nu_p, pk, y1, ne);
    sweep_kernel<false><<<gridE, BLOCK, 0, stream>>>(pk, y1, y2, x, eps_p, k_p, nu_p, out, ne);
    sweep_kernel<true ><<<gridE / 8, BLOCK, 0, stream>>>(pk, y2, nullptr, x, eps_p, k_p, nu_p, out, ne);
  }
}

// Round 5
// 849.828 us; speedup vs baseline: 2.0166x; 2.0166x over previous
//
#include <hip/hip_runtime.h>
#include <hip/hip_fp16.h>

// LaplacianKnn:  y'[i] = a*y[i] + b * sum_j m_e * y[nbr_e],  out = dot(x, y_nu)
// R6: gathers L2-hit, request-limited ~237us/pass = 292 cy per gather
//     wave-instr per CU (4.5 cy/lane).
// R7: sc0 L1-bypass null -> not cache policy/line-fill BW.
// R8: scatter atomics 6.5x worse (memory-side, past XCD L2s). Dead.
// R9/R10: persistent mega-kernel (coop AND hand-rolled barrier) ~2x slower.
//     Fusion dead; 4-dispatch structure is the base.
// R11 (this): per-wave instruction-level MLP has NEVER been probed (all prior
//     kernels: exactly 1 outstanding gather per wave; cross-wave concurrency
//     26/CU proven useless). sweep4 = 4 edges/thread: dwordx4 pk load + 4
//     independent gathers in flight before first vmcnt wait. A/B in-bench:
//     middle sweep = sweep4 (experiment), last sweep = scalar (237us control).
//     Fork: null (shared-pipe saturated; declare/bucket next) vs 100-160us.

typedef float  __attribute__((ext_vector_type(4))) floatx4;
typedef unsigned int uint32;
typedef uint32 __attribute__((ext_vector_type(4))) uint32x4;

static constexpr int BLOCK = 256;

// ---- pass 1 (coalesced only): z4[i] = half2(1/sum_j exp(-d/eps), x[i]) ----
__global__ __launch_bounds__(256) void dinv_kernel(
    const float* __restrict__ dist, const float* __restrict__ x,
    const float* __restrict__ eps_p,
    __half2* __restrict__ z4, int n_edges) {
  int t = blockIdx.x * BLOCK + threadIdx.x;
  int e4 = t << 2;
  if (e4 >= n_edges) return;
  float inv_eps = 1.0f / eps_p[0];
  floatx4 d = __builtin_nontemporal_load((const floatx4*)(dist + e4));
  float s = __expf(-d.x * inv_eps) + __expf(-d.y * inv_eps) +
            __expf(-d.z * inv_eps) + __expf(-d.w * inv_eps);
  #pragma unroll
  for (int off = 4; off > 0; off >>= 1) s += __shfl_down(s, off, 8);
  if ((t & 7) == 0) {
    int node = t >> 3;
    z4[node] = __halves2half2(__float2half(1.0f / s), __float2half(x[node]));
  }
}

// ---- pass 2 (fused pack + sweep 1): one 4B gather/edge from 4MB z4 ----
__global__ __launch_bounds__(256) void fsweep_kernel(
    const float* __restrict__ dist, const int* __restrict__ nbr,
    const __half2* __restrict__ z4,
    const float* __restrict__ x, const float* __restrict__ eps_p,
    const float* __restrict__ k_p, const int* __restrict__ nu_p,
    uint32* __restrict__ pk, float* __restrict__ yout, int n_edges) {
  int e = blockIdx.x * BLOCK + threadIdx.x;
  if (e >= n_edges) return;
  float inv_eps = 1.0f / eps_p[0];
  int j = __builtin_nontemporal_load(nbr + e);
  float d = __builtin_nontemporal_load(dist + e);
  __half2 z = z4[j];                       // PLAIN gather, L2-resident 4MB
  float t = __expf(-d * inv_eps) * __low2float(z);   // t_e = exp * Dinv[j]
  float g = t * __high2float(z);                     // t_e * x[j]
  float s = t;
  #pragma unroll
  for (int off = 1; off < 32; off <<= 1) s += __shfl_xor(s, off, 32);  // row sum
  float inv_s = 1.0f / s;
  uint32 mq = (uint32)__float2uint_rn(t * 4096.0f * inv_s);
  if (mq > 4095u) mq = 4095u;
  __builtin_nontemporal_store(((uint32)j << 12) | mq, pk + e);
  #pragma unroll
  for (int off = 16; off > 0; off >>= 1) g += __shfl_down(g, off, 32);
  if ((threadIdx.x & 31) == 0) {
    int node = e >> 5;
    float kk = k_p[0];
    float a = 4.0f * inv_eps + 2.0f * (float)nu_p[0] / (kk * kk) + 10.0f;
    float b = -4.0f * inv_eps;
    yout[node] = a * x[node] + b * g * inv_s;   // PLAIN store: keep y hot in L2
  }
}

// ---- sweep (x4 MLP experiment): 4 edges/thread, 4 gathers in flight ----
__global__ __launch_bounds__(256) void sweep4_kernel(
    const uint32* __restrict__ pk,
    const float* __restrict__ yin, float* __restrict__ yout,
    const float* __restrict__ eps_p, const float* __restrict__ k_p,
    const int* __restrict__ nu_p, int n_edges) {
  int t = blockIdx.x * BLOCK + threadIdx.x;
  int e4 = t << 2;
  if (e4 >= n_edges) return;
  float inv_eps = 1.0f / eps_p[0];
  float kk = k_p[0];
  float a  = 4.0f * inv_eps + 2.0f * (float)nu_p[0] / (kk * kk) + 10.0f;
  float bq = -4.0f * inv_eps * (1.0f / 4096.0f);
  uint32x4 p = __builtin_nontemporal_load((const uint32x4*)(pk + e4));
  // 4 independent gathers: compiler issues all before first vmcnt use-wait
  float v0 = yin[p.x >> 12];
  float v1 = yin[p.y >> 12];
  float v2 = yin[p.z >> 12];
  float v3 = yin[p.w >> 12];
  float g = (float)(p.x & 0xFFFu) * v0 + (float)(p.y & 0xFFFu) * v1 +
            (float)(p.z & 0xFFFu) * v2 + (float)(p.w & 0xFFFu) * v3;
  #pragma unroll
  for (int off = 4; off > 0; off >>= 1) g += __shfl_down(g, off, 8);  // 8 lanes = 1 row
  if ((t & 7) == 0) {
    int node = t >> 3;
    yout[node] = a * yin[node] + bq * g;
  }
}

// ---- last sweep: scalar control (expected pinned at ~237us) ----
template <bool LAST>
__global__ __launch_bounds__(256) void sweep_kernel(
    const uint32* __restrict__ pk,
    const float* __restrict__ yin, float* __restrict__ yout,
    const float* __restrict__ x,
    const float* __restrict__ eps_p, const float* __restrict__ k_p,
    const int* __restrict__ nu_p,
    float* __restrict__ out, int n_edges) {
  __shared__ float bsum;
  if (LAST) { if (threadIdx.x == 0) bsum = 0.0f; __syncthreads(); }
  float inv_eps = 1.0f / eps_p[0];
  float kk = k_p[0];
  float a  = 4.0f * inv_eps + 2.0f * (float)nu_p[0] / (kk * kk) + 10.0f;
  float bq = -4.0f * inv_eps * (1.0f / 4096.0f);
  int stride = gridDim.x * BLOCK;
  for (int e = blockIdx.x * BLOCK + threadIdx.x; e < n_edges; e += stride) {
    uint32 p = __builtin_nontemporal_load(pk + e);
    float g = (float)(p & 0xFFFu) * yin[p >> 12];
    #pragma unroll
    for (int off = 16; off > 0; off >>= 1) g += __shfl_down(g, off, 32);
    if ((threadIdx.x & 31) == 0) {
      int node = e >> 5;
      float ynew = a * yin[node] + bq * g;
      if (LAST) atomicAdd(&bsum, x[node] * ynew);
      else yout[node] = ynew;
    }
  }
  if (LAST) { __syncthreads(); if (threadIdx.x == 0) atomicAdd(out, bsum); }
}

extern "C" void kernel_launch(void* const* d_in, const int* in_sizes, int n_in,
                              void* d_out, int out_size, void* d_ws, size_t ws_size,
                              hipStream_t stream) {
  const float* x     = (const float*)d_in[0];
  const int*   nbr   = (const int*)d_in[1];
  const float* dist  = (const float*)d_in[2];
  const float* eps_p = (const float*)d_in[3];
  const float* k_p   = (const float*)d_in[4];
  const int*   nu_p  = (const int*)d_in[5];
  float* out = (float*)d_out;

  int n  = in_sizes[0];   // 1,000,000 nodes  (< 2^20 -> 20-bit index fits)
  int ne = in_sizes[1];   // 32,000,000 edges

  uint32* pk   = (uint32*)d_ws;         // [ne]  packed edges
  __half2* z4  = (__half2*)(pk + ne);   // [n]   (Dinv, x) in f16
  float* y1    = (float*)(z4 + n);      // [n]
  float* y2    = y1 + n;                // [n]

  (void)hipMemsetAsync(d_out, 0, sizeof(float), stream);

  int gridE = (ne + BLOCK - 1) / BLOCK;            // 1 edge/thread
  int grid4 = (ne + BLOCK * 4 - 1) / (BLOCK * 4);  // 4 edges/thread
  dinv_kernel<<<grid4, BLOCK, 0, stream>>>(dist, x, eps_p, z4, ne);
  fsweep_kernel<<<gridE, BLOCK, 0, stream>>>(dist, nbr, z4, x, eps_p, k_p, nu_p, pk, y1, ne);
  sweep4_kernel<<<grid4, BLOCK, 0, stream>>>(pk, y1, y2, eps_p, k_p, nu_p, ne);
  sweep_kernel<true><<<gridE / 8, BLOCK, 0, stream>>>(pk, y2, nullptr, x, eps_p, k_p, nu_p, out, ne);
}